// Round 15
// baseline (79.316 us; speedup 1.0000x reference)
//
#include <hip/hip_runtime.h>
#include <math.h>

#define N_IMG 12
#define C_IN 64
#define HFEAT 28
#define WFEAT 50
#define P_PIX 1400
#define ND 32
#define CB 128
#define BH 128
#define BW 128
#define BEPS 1e-5f

typedef float f32x4 __attribute__((ext_vector_type(4)));
typedef __bf16 bf16x8 __attribute__((ext_vector_type(8)));

__device__ __forceinline__ float gelu_exact(float x) {
  return 0.5f * x * (1.0f + erff(x * 0.70710678118654752440f));
}

// ---------------- prep: transpose + weight preps + bev zero ------------------
__global__ __launch_bounds__(256) void k_prep(
    const float* __restrict__ feat, const float* __restrict__ dh_w1,
    const float* __restrict__ br_w1, const float* __restrict__ br_w2,
    const float* __restrict__ fp_w, const float* __restrict__ dh_w2,
    __bf16* __restrict__ featT, __bf16* __restrict__ w1dh,
    __bf16* __restrict__ w1bev, __bf16* __restrict__ w2bev,
    __bf16* __restrict__ wfpbf, __bf16* __restrict__ w2bf,
    float* __restrict__ bev) {
  if (blockIdx.x < 264) {
    __shared__ float t[64][65];
    const int n = blockIdx.x / 22;
    const int p0 = (blockIdx.x % 22) * 64;
    const float* fb = feat + (size_t)n * C_IN * P_PIX;
    const int lane = threadIdx.x & 63;
    const int grp = threadIdx.x >> 6;
#pragma unroll
    for (int j = 0; j < 16; ++j) {
      int ci = j * 4 + grp;
      int px = p0 + lane;
      t[ci][lane] = (px < P_PIX) ? fb[ci * P_PIX + px] : 0.f;
    }
    __syncthreads();
#pragma unroll
    for (int k = 0; k < 2; ++k) {
      int gid = threadIdx.x * 2 + k;
      int pxl = gid >> 3, g = gid & 7;
      int px = p0 + pxl;
      if (px < P_PIX) {
        __bf16 tmp[8];
#pragma unroll
        for (int j = 0; j < 8; ++j) tmp[j] = (__bf16)t[g * 8 + j][pxl];
        *(bf16x8*)(featT + ((size_t)n * P_PIX + px) * C_IN + g * 8) = *(bf16x8*)tmp;
      }
    }
  } else if (blockIdx.x < 1600) {
    int idx = (blockIdx.x - 264) * 256 + threadIdx.x;
    if (idx < 36864) {
      int ci = idx & 63, co = (idx >> 6) & 63, tap = idx >> 12;
      w1dh[idx] = (__bf16)dh_w1[(co * 64 + ci) * 9 + tap];
    } else if (idx < 36864 + 147456) {
      int k = idx - 36864;
      int e = k & 7, lane = (k >> 3) & 63, cb = (k >> 9) & 7;
      int ks = (k >> 12) & 3, tap = k >> 14;
      int co = cb * 16 + (lane & 15);
      int ci = ks * 32 + (lane >> 4) * 8 + e;
      w1bev[k] = (__bf16)br_w1[((size_t)co * CB + ci) * 9 + tap];
    } else if (idx < 36864 + 2 * 147456) {
      int k = idx - 36864 - 147456;
      int e = k & 7, lane = (k >> 3) & 63, cb = (k >> 9) & 7;
      int ks = (k >> 12) & 3, tap = k >> 14;
      int co = cb * 16 + (lane & 15);
      int ci = ks * 32 + (lane >> 4) * 8 + e;
      w2bev[k] = (__bf16)br_w2[((size_t)co * CB + ci) * 9 + tap];
    } else if (idx < 36864 + 2 * 147456 + 8192) {
      int k = idx - 36864 - 2 * 147456;
      wfpbf[k] = (__bf16)fp_w[k];
    } else if (idx < 36864 + 2 * 147456 + 8192 + 2048) {
      int k = idx - 36864 - 2 * 147456 - 8192;
      w2bf[k] = (__bf16)dh_w2[k];
    }
  } else {
    size_t off = ((size_t)(blockIdx.x - 1600) * 256 + threadIdx.x) * 4;
    *(float4*)(bev + off) = make_float4(0.f, 0.f, 0.f, 0.f);
  }
}

// ---------------- mega front v8: asm-pinned register weight prefetch ---------
#define FA_O 0        // [3 kx][16 i][64 ci] bf16 = 6144
#define HL_O 6144     // [16 px][64 co] bf16 swizzled = 2048
#define FL_O 8192     // [16 px][132] f32 = 8448
#define DP_O 16640    // [14 px][33] f32 = 1848
#define GEO_O 18496   // vL[32] colL[32] rowL[32] = 384
#define G_O 18880     // [32 d][128 c] f32 = 16384
#define LDS_TOT 35264

__global__ __launch_bounds__(256, 2) void k_mega(
    const __bf16* __restrict__ featT, const __bf16* __restrict__ w1bf,
    const float* __restrict__ dh_b1, const float* __restrict__ dh_g,
    const float* __restrict__ dh_be, const float* __restrict__ dh_m,
    const float* __restrict__ dh_v, const __bf16* __restrict__ w2bf,
    const float* __restrict__ dh_b2, const __bf16* __restrict__ wfpbf,
    const float* __restrict__ fp_b, const float* __restrict__ fp_g,
    const float* __restrict__ fp_be, const float* __restrict__ fp_m,
    const float* __restrict__ fp_v, const float* __restrict__ trust,
    const float* __restrict__ Kmat, const float* __restrict__ Tmat,
    float* __restrict__ bev) {
  __shared__ __align__(16) unsigned char lds[LDS_TOT];
  const int blk = blockIdx.x;
  const int n = blk / 100;
  const int rem = blk % 100;
  const int rh = rem / 50;
  const int xc = rem % 50;
  const int r0 = rh * 14;
  const int tid = threadIdx.x;
  const int l = tid & 63;
  const int wid = tid >> 6;
  const int lrow = l & 15;
  const int kgrp = l >> 4;
  int* vL = (int*)(lds + GEO_O);
  int* colL = vL + 32;
  int* rowL = colL + 32;

  // ---- issue ALL weight-fragment loads first (18 dh + 2 fp + 2 w2) ----
  const int co_h = wid * 16 + lrow;
  bf16x8 wfr[18], wfp[2], w2r[2];
#pragma unroll
  for (int tap = 0; tap < 9; ++tap)
#pragma unroll
    for (int ks = 0; ks < 2; ++ks)
      wfr[tap * 2 + ks] =
          *(const bf16x8*)(w1bf + tap * 4096 + co_h * 64 + (ks * 4 + kgrp) * 8);
#pragma unroll
  for (int ks = 0; ks < 2; ++ks) {
    wfp[ks] = *(const bf16x8*)(wfpbf + ((wid & 1) * 32 + (wid >> 1) * 16 + lrow) * 64 +
                               (ks * 4 + kgrp) * 8);
  }
  // NOTE: fp conv below uses co = wid*32 + fn*16 + lrow; to keep static layout
  // we load both fn fragments per ks instead:
  bf16x8 wfpf[2][2];
#pragma unroll
  for (int ks = 0; ks < 2; ++ks)
#pragma unroll
    for (int fn = 0; fn < 2; ++fn)
      wfpf[ks][fn] = *(const bf16x8*)(wfpbf + (wid * 32 + fn * 16 + lrow) * 64 +
                                      (ks * 4 + kgrp) * 8);
#pragma unroll
  for (int ks = 0; ks < 2; ++ks)
    w2r[ks] = *(const bf16x8*)(w2bf + ((wid & 1) * 16 + lrow) * 64 +
                               (ks * 4 + kgrp) * 8);

  // ---- stage FA: 3 cols x 16 rows (r0-1 .. r0+14) x 64ci ----
  {
    const __bf16* fT = featT + (size_t)n * P_PIX * C_IN;
    for (int i2 = tid; i2 < 384; i2 += 256) {
      int q = i2 >> 3, g = i2 & 7;
      int kx = q >> 4, i = q & 15;
      int row = r0 - 1 + i, col = xc - 1 + kx;
      bf16x8 val;
      if (row >= 0 && row < HFEAT && col >= 0 && col < WFEAT) {
        val = *(const bf16x8*)(fT + ((size_t)(row * WFEAT + col)) * C_IN + g * 8);
      } else {
        __bf16 z[8] = {};
        val = *(bf16x8*)z;
      }
      *(bf16x8*)(lds + FA_O + q * 128 + ((g ^ (q & 7)) << 4)) = val;
    }
  }

  // ---- geometry per depth (bit-identical to prior rounds) ----
  if (tid < 32) {
    int d = tid;
    const float* Kp = Kmat + n * 9;
    float fx = Kp[0], cx = Kp[2];
    float rx = ((float)xc - cx) / fx;
    const float* Tp = Tmat + n * 16;
    float depth = 1.0f + (float)d * (49.0f / 31.0f);
    float pcx = rx * depth, pcz = depth;
    float Xx = Tp[0] * pcx + Tp[2] * pcz + Tp[3];
    float Xy = Tp[4] * pcx + Tp[6] * pcz + Tp[7];
    float uf = (Xx + 20.0f) / 40.0f * 127.0f;
    float vf = (Xy + 20.0f) / 40.0f * 127.0f;
    vL[d] = (uf > -1.0f && uf < 128.0f && vf > -1.0f && vf < 128.0f) ? 1 : 0;
    colL[d] = (int)uf;
    rowL[d] = (int)vf;
  }

  // ---- PIN the prefetched fragments here (rule #17: prevents sinking) ----
#pragma unroll
  for (int i = 0; i < 18; ++i) asm volatile("" : "+v"(wfr[i]));
#pragma unroll
  for (int ks = 0; ks < 2; ++ks) {
    asm volatile("" : "+v"(wfpf[ks][0]));
    asm volatile("" : "+v"(wfpf[ks][1]));
    asm volatile("" : "+v"(w2r[ks]));
  }
  __syncthreads();  // barrier 1

  // ---- dh 3x3 conv MFMA: register B operands ----
  f32x4 acc_h = {0.f, 0.f, 0.f, 0.f};
  const int p_h = lrow < 14 ? lrow : 13;
#pragma unroll
  for (int tap = 0; tap < 9; ++tap) {
    const int ky = tap / 3, kx = tap % 3;
#pragma unroll
    for (int ks = 0; ks < 2; ++ks) {
      const int gran = ks * 4 + kgrp;
      int q = kx * 16 + p_h + ky;
      bf16x8 afr = *(const bf16x8*)(lds + FA_O + q * 128 + ((gran ^ (q & 7)) << 4));
      acc_h = __builtin_amdgcn_mfma_f32_16x16x32_bf16(afr, wfr[tap * 2 + ks],
                                                      acc_h, 0, 0, 0);
    }
  }

  // ---- fp 1x1 conv MFMA: register B operands ----
  f32x4 acc_fp[2];
  acc_fp[0] = {0.f, 0.f, 0.f, 0.f};
  acc_fp[1] = {0.f, 0.f, 0.f, 0.f};
#pragma unroll
  for (int ks = 0; ks < 2; ++ks) {
    const int gran = ks * 4 + kgrp;
    int q = 16 + p_h + 1;
    bf16x8 afr = *(const bf16x8*)(lds + FA_O + q * 128 + ((gran ^ (q & 7)) << 4));
#pragma unroll
    for (int fn = 0; fn < 2; ++fn)
      acc_fp[fn] = __builtin_amdgcn_mfma_f32_16x16x32_bf16(afr, wfpf[ks][fn],
                                                           acc_fp[fn], 0, 0, 0);
  }

  // ---- h epilogue: BN + GELU -> HL bf16 (swizzled) ----
  {
    float sc = dh_g[co_h] / sqrtf(dh_v[co_h] + BEPS);
    float sh = dh_be[co_h] - dh_m[co_h] * sc + dh_b1[co_h] * sc;
#pragma unroll
    for (int rr = 0; rr < 4; ++rr) {
      int px = kgrp * 4 + rr;
      float val = gelu_exact(acc_h[rr] * sc + sh);
      *(__bf16*)(lds + HL_O + px * 128 + (((co_h >> 3) ^ (px & 7)) << 4) +
                 (co_h & 7) * 2) = (__bf16)val;
    }
  }
  // ---- fp epilogue: BN + GELU -> FL f32 ----
  {
    float* FLf = (float*)(lds + FL_O);
#pragma unroll
    for (int fn = 0; fn < 2; ++fn) {
      int co = wid * 32 + fn * 16 + lrow;
      float sc = fp_g[co] / sqrtf(fp_v[co] + BEPS);
      float sh = fp_be[co] - fp_m[co] * sc + fp_b[co] * sc;
#pragma unroll
      for (int rr = 0; rr < 4; ++rr) {
        int px = kgrp * 4 + rr;
        FLf[px * 132 + co] = gelu_exact(acc_fp[fn][rr] * sc + sh);
      }
    }
  }
  __syncthreads();  // barrier 2

  // ---- depth logits MFMA (waves 0,1): register B operands ----
  if (wid < 2) {
    f32x4 acc_l = {0.f, 0.f, 0.f, 0.f};
    const int dcol = wid * 16 + lrow;
#pragma unroll
    for (int ks = 0; ks < 2; ++ks) {
      const int gran = ks * 4 + kgrp;
      bf16x8 afr = *(const bf16x8*)(lds + HL_O + lrow * 128 +
                                    ((gran ^ (lrow & 7)) << 4));
      acc_l = __builtin_amdgcn_mfma_f32_16x16x32_bf16(afr, w2r[ks], acc_l, 0, 0, 0);
    }
    float b2v = dh_b2[dcol];
    float* dp = (float*)(lds + DP_O);
#pragma unroll
    for (int rr = 0; rr < 4; ++rr) {
      int px = kgrp * 4 + rr;
      if (px < 14) dp[px * 33 + dcol] = acc_l[rr] + b2v;
    }
  }
  __syncthreads();  // barrier 3

  // ---- wave-parallel softmax: 8 lanes per px, 4 depths each ----
  {
    float* dp = (float*)(lds + DP_O);
    int px = tid >> 3, dg = tid & 7;
    if (px < 14) {
      float l0 = dp[px * 33 + dg * 4 + 0];
      float l1 = dp[px * 33 + dg * 4 + 1];
      float l2 = dp[px * 33 + dg * 4 + 2];
      float l3 = dp[px * 33 + dg * 4 + 3];
      float mx = fmaxf(fmaxf(l0, l1), fmaxf(l2, l3));
      mx = fmaxf(mx, __shfl_xor(mx, 1));
      mx = fmaxf(mx, __shfl_xor(mx, 2));
      mx = fmaxf(mx, __shfl_xor(mx, 4));
      float e0 = expf(l0 - mx), e1 = expf(l1 - mx);
      float e2 = expf(l2 - mx), e3 = expf(l3 - mx);
      float s = (e0 + e1) + (e2 + e3);
      s += __shfl_xor(s, 1);
      s += __shfl_xor(s, 2);
      s += __shfl_xor(s, 4);
      float inv = trust[n] / s;
      dp[px * 33 + dg * 4 + 0] = e0 * inv;
      dp[px * 33 + dg * 4 + 1] = e1 * inv;
      dp[px * 33 + dg * 4 + 2] = e2 * inv;
      dp[px * 33 + dg * 4 + 3] = e3 * inv;
    }
  }
  __syncthreads();  // barrier 4

  // ---- partial G[d][c] = sum_{r in half} dp[r][d]*F[r][c] ----
  {
    const int d = tid >> 3, cg = tid & 7;
    if (vL[d]) {
      const float* dp = (const float*)(lds + DP_O);
      const float* FLf = (const float*)(lds + FL_O);
      float a[16];
#pragma unroll
      for (int j = 0; j < 16; ++j) a[j] = 0.f;
      for (int r = 0; r < 14; ++r) {
        float dv = dp[r * 33 + d];
        const float4* fr = (const float4*)(FLf + r * 132 + cg * 16);
        float4 f0 = fr[0], f1 = fr[1], f2 = fr[2], f3 = fr[3];
        a[0] = fmaf(dv, f0.x, a[0]);   a[1] = fmaf(dv, f0.y, a[1]);
        a[2] = fmaf(dv, f0.z, a[2]);   a[3] = fmaf(dv, f0.w, a[3]);
        a[4] = fmaf(dv, f1.x, a[4]);   a[5] = fmaf(dv, f1.y, a[5]);
        a[6] = fmaf(dv, f1.z, a[6]);   a[7] = fmaf(dv, f1.w, a[7]);
        a[8] = fmaf(dv, f2.x, a[8]);   a[9] = fmaf(dv, f2.y, a[9]);
        a[10] = fmaf(dv, f2.z, a[10]); a[11] = fmaf(dv, f2.w, a[11]);
        a[12] = fmaf(dv, f3.x, a[12]); a[13] = fmaf(dv, f3.y, a[13]);
        a[14] = fmaf(dv, f3.z, a[14]); a[15] = fmaf(dv, f3.w, a[15]);
      }
      float* gw = (float*)(lds + G_O) + d * 128 + cg * 16;
#pragma unroll
      for (int j = 0; j < 16; ++j) gw[j] = a[j];
    }
  }
  __syncthreads();  // barrier 5

  // ---- coalesced atomics: lanes = contiguous channels; staggered d ----
  {
    const int hd = tid >> 7;
    const int c = tid & 127;
    const int b = n / 6;
    const float* Gf = (const float*)(lds + G_O);
    float* bb = bev + ((size_t)b * (BH * BW)) * CB + c;
    for (int it = 0; it < 16; ++it) {
      int d = ((it + (int)blockIdx.x) & 15) * 2 + hd;
      if (vL[d])
        atomicAdd(bb + ((size_t)rowL[d] * BW + colL[d]) * CB, Gf[d * 128 + c]);
    }
  }
}

// ---------------- BEV 3x3 conv via bf16 MFMA: 8x4 tiles, 1024 blocks --------
template <int IN_F32, int OUT_NCHW>
__global__ __launch_bounds__(256, 4) void k_bev_conv_mfma(
    const void* __restrict__ inp, const __bf16* __restrict__ wt2,
    const float* __restrict__ bias, const float* __restrict__ g,
    const float* __restrict__ be, const float* __restrict__ m,
    const float* __restrict__ v, void* __restrict__ outp) {
  __shared__ __align__(16) unsigned char ldsA[60 * CB * 2];
  __shared__ float lo[OUT_NCHW ? 32 * 130 : 4];

  const int blk = blockIdx.x;
  const int tx = blk & 15;
  const int ty = (blk >> 4) & 31;
  const int b = blk >> 9;
  const int y0 = ty * 4, x0 = tx * 8;

  const int l = threadIdx.x & 63;
  const int wid = threadIdx.x >> 6;
  const int lrow = l & 15;
  const int kgrp = l >> 4;

  for (int i = threadIdx.x; i < 960; i += 256) {
    int q = i >> 4;
    int ch = i & 15;
    int hy = q / 10, hx = q % 10;
    int gy = y0 + hy - 1, gx = x0 + hx - 1;
    bf16x8 val;
    if (gy >= 0 && gy < BH && gx >= 0 && gx < BW) {
      if (IN_F32) {
        const float* ib = (const float*)inp + (size_t)b * BH * BW * CB;
        const float* sp = ib + ((size_t)gy * BW + gx) * CB + ch * 8;
        float4 a = *(const float4*)sp;
        float4 bb = *(const float4*)(sp + 4);
        __bf16 tmp[8] = {(__bf16)a.x,  (__bf16)a.y,  (__bf16)a.z,  (__bf16)a.w,
                         (__bf16)bb.x, (__bf16)bb.y, (__bf16)bb.z, (__bf16)bb.w};
        val = *(bf16x8*)tmp;
      } else {
        const __bf16* ib = (const __bf16*)inp + (size_t)b * BH * BW * CB;
        val = *(const bf16x8*)(ib + ((size_t)gy * BW + gx) * CB + ch * 8);
      }
    } else {
      __bf16 tmp[8] = {(__bf16)0.f, (__bf16)0.f, (__bf16)0.f, (__bf16)0.f,
                       (__bf16)0.f, (__bf16)0.f, (__bf16)0.f, (__bf16)0.f};
      val = *(bf16x8*)tmp;
    }
    int byte = (q * 256 + ch * 16) ^ ((q & 7) << 4);
    *(bf16x8*)(ldsA + byte) = val;
  }
  __syncthreads();

  f32x4 acc[2][2];
#pragma unroll
  for (int i = 0; i < 2; ++i)
#pragma unroll
    for (int j = 0; j < 2; ++j) acc[i][j] = {0.f, 0.f, 0.f, 0.f};

#pragma unroll
  for (int tap = 0; tap < 9; ++tap) {
    const int ky = tap / 3, kx = tap % 3;
#pragma unroll
    for (int ks = 0; ks < 4; ++ks) {
      const int ci0b = (ks * 32 + kgrp * 8) * 2;
      bf16x8 afr[2], bfr[2];
#pragma unroll
      for (int fm = 0; fm < 2; ++fm) {
        int mpx = fm * 16 + lrow;
        int q = ((mpx >> 3) + ky) * 10 + (mpx & 7) + kx;
        int byte = (q * 256 + ci0b) ^ ((q & 7) << 4);
        afr[fm] = *(const bf16x8*)(ldsA + byte);
      }
#pragma unroll
      for (int fn = 0; fn < 2; ++fn) {
        int frag = (tap * 4 + ks) * 8 + (wid * 2 + fn);
        bfr[fn] = *(const bf16x8*)(wt2 + ((size_t)frag << 9) + (l << 3));
      }
#pragma unroll
      for (int fm = 0; fm < 2; ++fm)
#pragma unroll
        for (int fn = 0; fn < 2; ++fn)
          acc[fm][fn] = __builtin_amdgcn_mfma_f32_16x16x32_bf16(
              afr[fm], bfr[fn], acc[fm][fn], 0, 0, 0);
    }
  }

  if (OUT_NCHW == 0) {
    __bf16* out = (__bf16*)outp;
#pragma unroll
    for (int fn = 0; fn < 2; ++fn) {
      int co = wid * 32 + fn * 16 + lrow;
      float sc = g[co] / sqrtf(v[co] + BEPS);
      float sh = be[co] - m[co] * sc + bias[co] * sc;
#pragma unroll
      for (int fm = 0; fm < 2; ++fm) {
#pragma unroll
        for (int r = 0; r < 4; ++r) {
          int mpx = fm * 16 + kgrp * 4 + r;
          int y = y0 + (mpx >> 3), x = x0 + (mpx & 7);
          float val = gelu_exact(acc[fm][fn][r] * sc + sh);
          out[((size_t)(b * BH + y) * BW + x) * CB + co] = (__bf16)val;
        }
      }
    }
  } else {
#pragma unroll
    for (int fn = 0; fn < 2; ++fn) {
      int co = wid * 32 + fn * 16 + lrow;
      float sc = g[co] / sqrtf(v[co] + BEPS);
      float sh = be[co] - m[co] * sc + bias[co] * sc;
#pragma unroll
      for (int fm = 0; fm < 2; ++fm) {
#pragma unroll
        for (int r = 0; r < 4; ++r) {
          int mpx = fm * 16 + kgrp * 4 + r;
          lo[mpx * 130 + co] = gelu_exact(acc[fm][fn][r] * sc + sh);
        }
      }
    }
    __syncthreads();
    float* out = (float*)outp;
    for (int pair = threadIdx.x; pair < 512; pair += 256) {
      int co = pair >> 2, py = pair & 3;
      float tmp[8];
#pragma unroll
      for (int i = 0; i < 8; ++i) tmp[i] = lo[(py * 8 + i) * 130 + co];
      float* op = out + (((size_t)(b * CB + co) * BH) + (y0 + py)) * BW + x0;
      *(float4*)op = *(float4*)tmp;
      *(float4*)(op + 4) = *(float4*)(tmp + 4);
    }
  }
}

extern "C" void kernel_launch(void* const* d_in, const int* in_sizes, int n_in,
                              void* d_out, int out_size, void* d_ws, size_t ws_size,
                              hipStream_t stream) {
  const float* feat = (const float*)d_in[0];
  const float* Kmat = (const float*)d_in[1];
  const float* Tmat = (const float*)d_in[2];
  const float* trust = (const float*)d_in[3];
  const float* dh_w1 = (const float*)d_in[4];
  const float* dh_b1 = (const float*)d_in[5];
  const float* dh_g = (const float*)d_in[6];
  const float* dh_be = (const float*)d_in[7];
  const float* dh_m = (const float*)d_in[8];
  const float* dh_v = (const float*)d_in[9];
  const float* dh_w2 = (const float*)d_in[10];
  const float* dh_b2 = (const float*)d_in[11];
  const float* fp_w = (const float*)d_in[12];
  const float* fp_b = (const float*)d_in[13];
  const float* fp_g = (const float*)d_in[14];
  const float* fp_be = (const float*)d_in[15];
  const float* fp_m = (const float*)d_in[16];
  const float* fp_v = (const float*)d_in[17];
  const float* br_w1 = (const float*)d_in[18];
  const float* br_b1 = (const float*)d_in[19];
  const float* br_g1 = (const float*)d_in[20];
  const float* br_be1 = (const float*)d_in[21];
  const float* br_m1 = (const float*)d_in[22];
  const float* br_v1 = (const float*)d_in[23];
  const float* br_w2 = (const float*)d_in[24];
  const float* br_b2 = (const float*)d_in[25];
  const float* br_g2 = (const float*)d_in[26];
  const float* br_be2 = (const float*)d_in[27];
  const float* br_m2 = (const float*)d_in[28];
  const float* br_v2 = (const float*)d_in[29];

  float* ws = (float*)d_ws;
  float* bev = ws;                                       // 4,194,304 f
  float* after = bev + 4194304;
  __bf16* h1bf = (__bf16*)after;                         // 4,194,304 bf16
  __bf16* w1dh = (__bf16*)(after + 2097152);             // 36,864 bf16
  __bf16* w1bev = (__bf16*)(after + 2097152 + 18432);    // 147,456 bf16 (frag order)
  __bf16* w2bev = (__bf16*)(after + 2097152 + 18432 + 73728);        // 147,456
  __bf16* wfpbf = (__bf16*)(after + 2097152 + 18432 + 2 * 73728);    // 8,192
  __bf16* w2bf = (__bf16*)(after + 2097152 + 18432 + 2 * 73728 + 4096);  // 2,048
  __bf16* featT = (__bf16*)(after + 2097152 + 18432 + 2 * 73728 + 4096 + 1024);

  // prep: transpose + weight preps + bev zero (1 dispatch)
  k_prep<<<5696, 256, 0, stream>>>(feat, dh_w1, br_w1, br_w2, fp_w, dh_w2,
                                   featT, w1dh, w1bev, w2bev, wfpbf, w2bf, bev);
  // fused front v8 (row-split + pinned register weight prefetch)
  k_mega<<<N_IMG * WFEAT * 2, 256, 0, stream>>>(
      featT, w1dh, dh_b1, dh_g, dh_be, dh_m, dh_v, w2bf, dh_b2, wfpbf, fp_b,
      fp_g, fp_be, fp_m, fp_v, trust, Kmat, Tmat, bev);
  // BEV refinement convs via MFMA (8x4 tiles: 1024 blocks each)
  k_bev_conv_mfma<1, 0><<<1024, 256, 0, stream>>>(
      (const void*)bev, w1bev, br_b1, br_g1, br_be1, br_m1, br_v1, (void*)h1bf);
  k_bev_conv_mfma<0, 1><<<1024, 256, 0, stream>>>(
      (const void*)h1bf, w2bev, br_b2, br_g2, br_be2, br_m2, br_v2, d_out);
}

// Round 16
// 77.219 us; speedup vs baseline: 1.0272x; 1.0272x over previous
//
#include <hip/hip_runtime.h>
#include <math.h>

#define N_IMG 12
#define C_IN 64
#define HFEAT 28
#define WFEAT 50
#define P_PIX 1400
#define ND 32
#define CB 128
#define BH 128
#define BW 128
#define BEPS 1e-5f

typedef float f32x4 __attribute__((ext_vector_type(4)));
typedef __bf16 bf16x8 __attribute__((ext_vector_type(8)));

__device__ __forceinline__ float gelu_exact(float x) {
  return 0.5f * x * (1.0f + erff(x * 0.70710678118654752440f));
}

// ---------------- prep: transpose + weight preps + bev zero ------------------
__global__ __launch_bounds__(256) void k_prep(
    const float* __restrict__ feat, const float* __restrict__ dh_w1,
    const float* __restrict__ br_w1, const float* __restrict__ br_w2,
    const float* __restrict__ fp_w, const float* __restrict__ dh_w2,
    __bf16* __restrict__ featT, __bf16* __restrict__ w1dh,
    __bf16* __restrict__ w1bev, __bf16* __restrict__ w2bev,
    __bf16* __restrict__ wfpbf, __bf16* __restrict__ w2bf,
    float* __restrict__ bev) {
  if (blockIdx.x < 264) {
    __shared__ float t[64][65];
    const int n = blockIdx.x / 22;
    const int p0 = (blockIdx.x % 22) * 64;
    const float* fb = feat + (size_t)n * C_IN * P_PIX;
    const int lane = threadIdx.x & 63;
    const int grp = threadIdx.x >> 6;
#pragma unroll
    for (int j = 0; j < 16; ++j) {
      int ci = j * 4 + grp;
      int px = p0 + lane;
      t[ci][lane] = (px < P_PIX) ? fb[ci * P_PIX + px] : 0.f;
    }
    __syncthreads();
#pragma unroll
    for (int k = 0; k < 2; ++k) {
      int gid = threadIdx.x * 2 + k;
      int pxl = gid >> 3, g = gid & 7;
      int px = p0 + pxl;
      if (px < P_PIX) {
        __bf16 tmp[8];
#pragma unroll
        for (int j = 0; j < 8; ++j) tmp[j] = (__bf16)t[g * 8 + j][pxl];
        *(bf16x8*)(featT + ((size_t)n * P_PIX + px) * C_IN + g * 8) = *(bf16x8*)tmp;
      }
    }
  } else if (blockIdx.x < 1600) {
    int idx = (blockIdx.x - 264) * 256 + threadIdx.x;
    if (idx < 36864) {
      int ci = idx & 63, co = (idx >> 6) & 63, tap = idx >> 12;
      w1dh[idx] = (__bf16)dh_w1[(co * 64 + ci) * 9 + tap];
    } else if (idx < 36864 + 147456) {
      int k = idx - 36864;
      int e = k & 7, lane = (k >> 3) & 63, cb = (k >> 9) & 7;
      int ks = (k >> 12) & 3, tap = k >> 14;
      int co = cb * 16 + (lane & 15);
      int ci = ks * 32 + (lane >> 4) * 8 + e;
      w1bev[k] = (__bf16)br_w1[((size_t)co * CB + ci) * 9 + tap];
    } else if (idx < 36864 + 2 * 147456) {
      int k = idx - 36864 - 147456;
      int e = k & 7, lane = (k >> 3) & 63, cb = (k >> 9) & 7;
      int ks = (k >> 12) & 3, tap = k >> 14;
      int co = cb * 16 + (lane & 15);
      int ci = ks * 32 + (lane >> 4) * 8 + e;
      w2bev[k] = (__bf16)br_w2[((size_t)co * CB + ci) * 9 + tap];
    } else if (idx < 36864 + 2 * 147456 + 8192) {
      int k = idx - 36864 - 2 * 147456;
      wfpbf[k] = (__bf16)fp_w[k];
    } else if (idx < 36864 + 2 * 147456 + 8192 + 2048) {
      int k = idx - 36864 - 2 * 147456 - 8192;
      w2bf[k] = (__bf16)dh_w2[k];
    }
  } else {
    size_t off = ((size_t)(blockIdx.x - 1600) * 256 + threadIdx.x) * 4;
    *(float4*)(bev + off) = make_float4(0.f, 0.f, 0.f, 0.f);
  }
}

// ---------------- mega front v5: row-split, 1200 blocks (round-12 best) ------
#define FA_O 0        // [3 kx][16 i][64 ci] bf16 = 6144
#define HL_O 6144     // [16 px][64 co] bf16 swizzled = 2048
#define FL_O 8192     // [16 px][132] f32 = 8448
#define DP_O 16640    // [14 px][33] f32 = 1848
#define GEO_O 18496   // vL[32] colL[32] rowL[32] = 384
#define G_O 18880     // [32 d][128 c] f32 = 16384
#define LDS_TOT 35264

__global__ __launch_bounds__(256, 4) void k_mega(
    const __bf16* __restrict__ featT, const __bf16* __restrict__ w1bf,
    const float* __restrict__ dh_b1, const float* __restrict__ dh_g,
    const float* __restrict__ dh_be, const float* __restrict__ dh_m,
    const float* __restrict__ dh_v, const __bf16* __restrict__ w2bf,
    const float* __restrict__ dh_b2, const __bf16* __restrict__ wfpbf,
    const float* __restrict__ fp_b, const float* __restrict__ fp_g,
    const float* __restrict__ fp_be, const float* __restrict__ fp_m,
    const float* __restrict__ fp_v, const float* __restrict__ trust,
    const float* __restrict__ Kmat, const float* __restrict__ Tmat,
    float* __restrict__ bev) {
  __shared__ __align__(16) unsigned char lds[LDS_TOT];
  const int blk = blockIdx.x;
  const int n = blk / 100;
  const int rem = blk % 100;
  const int rh = rem / 50;
  const int xc = rem % 50;
  const int r0 = rh * 14;
  const int tid = threadIdx.x;
  const int l = tid & 63;
  const int wid = tid >> 6;
  const int lrow = l & 15;
  const int kgrp = l >> 4;
  int* vL = (int*)(lds + GEO_O);
  int* colL = vL + 32;
  int* rowL = colL + 32;

  // ---- geometry per depth (pure fn of (n,xc,d): identical in both halves) ----
  if (tid < 32) {
    int d = tid;
    const float* Kp = Kmat + n * 9;
    float fx = Kp[0], cx = Kp[2];
    float rx = ((float)xc - cx) / fx;
    const float* Tp = Tmat + n * 16;
    float depth = 1.0f + (float)d * (49.0f / 31.0f);
    float pcx = rx * depth, pcz = depth;
    float Xx = Tp[0] * pcx + Tp[2] * pcz + Tp[3];
    float Xy = Tp[4] * pcx + Tp[6] * pcz + Tp[7];
    float uf = (Xx + 20.0f) / 40.0f * 127.0f;
    float vf = (Xy + 20.0f) / 40.0f * 127.0f;
    vL[d] = (uf > -1.0f && uf < 128.0f && vf > -1.0f && vf < 128.0f) ? 1 : 0;
    colL[d] = (int)uf;
    rowL[d] = (int)vf;
  }

  // ---- stage FA: 3 cols x 16 rows (r0-1 .. r0+14) x 64ci ----
  {
    const __bf16* fT = featT + (size_t)n * P_PIX * C_IN;
    for (int i2 = tid; i2 < 384; i2 += 256) {
      int q = i2 >> 3, g = i2 & 7;
      int kx = q >> 4, i = q & 15;
      int row = r0 - 1 + i, col = xc - 1 + kx;
      bf16x8 val;
      if (row >= 0 && row < HFEAT && col >= 0 && col < WFEAT) {
        val = *(const bf16x8*)(fT + ((size_t)(row * WFEAT + col)) * C_IN + g * 8);
      } else {
        __bf16 z[8] = {};
        val = *(bf16x8*)z;
      }
      *(bf16x8*)(lds + FA_O + q * 128 + ((g ^ (q & 7)) << 4)) = val;
    }
  }
  __syncthreads();  // barrier 1

  // ---- dh 3x3 conv MFMA: M=14(16) px, N=64co (16/wave), K=576 ----
  f32x4 acc_h = {0.f, 0.f, 0.f, 0.f};
  const int co_h = wid * 16 + lrow;
  const int p_h = lrow < 14 ? lrow : 13;  // clamp pad lanes in-bounds
#pragma unroll
  for (int tap = 0; tap < 9; ++tap) {
    const int ky = tap / 3, kx = tap % 3;
#pragma unroll
    for (int ks = 0; ks < 2; ++ks) {
      const int gran = ks * 4 + kgrp;
      int q = kx * 16 + p_h + ky;
      bf16x8 afr = *(const bf16x8*)(lds + FA_O + q * 128 + ((gran ^ (q & 7)) << 4));
      bf16x8 bfr = *(const bf16x8*)(w1bf + tap * 4096 + co_h * 64 + gran * 8);
      acc_h = __builtin_amdgcn_mfma_f32_16x16x32_bf16(afr, bfr, acc_h, 0, 0, 0);
    }
  }

  // ---- fp 1x1 conv MFMA: M=14(16) px, N=128co (32/wave), K=64 ----
  f32x4 acc_fp[2];
  acc_fp[0] = {0.f, 0.f, 0.f, 0.f};
  acc_fp[1] = {0.f, 0.f, 0.f, 0.f};
#pragma unroll
  for (int ks = 0; ks < 2; ++ks) {
    const int gran = ks * 4 + kgrp;
    int q = 16 + p_h + 1;  // center tap plane (kx=1, ky=1)
    bf16x8 afr = *(const bf16x8*)(lds + FA_O + q * 128 + ((gran ^ (q & 7)) << 4));
#pragma unroll
    for (int fn = 0; fn < 2; ++fn) {
      int co = wid * 32 + fn * 16 + lrow;
      bf16x8 bfr = *(const bf16x8*)(wfpbf + co * 64 + gran * 8);
      acc_fp[fn] = __builtin_amdgcn_mfma_f32_16x16x32_bf16(afr, bfr, acc_fp[fn],
                                                           0, 0, 0);
    }
  }

  // ---- h epilogue: BN + GELU -> HL bf16 (swizzled) ----
  {
    float sc = dh_g[co_h] / sqrtf(dh_v[co_h] + BEPS);
    float sh = dh_be[co_h] - dh_m[co_h] * sc + dh_b1[co_h] * sc;
#pragma unroll
    for (int rr = 0; rr < 4; ++rr) {
      int px = kgrp * 4 + rr;
      float val = gelu_exact(acc_h[rr] * sc + sh);
      *(__bf16*)(lds + HL_O + px * 128 + (((co_h >> 3) ^ (px & 7)) << 4) +
                 (co_h & 7) * 2) = (__bf16)val;
    }
  }
  // ---- fp epilogue: BN + GELU -> FL f32 ----
  {
    float* FLf = (float*)(lds + FL_O);
#pragma unroll
    for (int fn = 0; fn < 2; ++fn) {
      int co = wid * 32 + fn * 16 + lrow;
      float sc = fp_g[co] / sqrtf(fp_v[co] + BEPS);
      float sh = fp_be[co] - fp_m[co] * sc + fp_b[co] * sc;
#pragma unroll
      for (int rr = 0; rr < 4; ++rr) {
        int px = kgrp * 4 + rr;
        FLf[px * 132 + co] = gelu_exact(acc_fp[fn][rr] * sc + sh);
      }
    }
  }
  __syncthreads();  // barrier 2

  // ---- depth logits MFMA (waves 0,1): M=14(16) px, N=32d, K=64 ----
  if (wid < 2) {
    f32x4 acc_l = {0.f, 0.f, 0.f, 0.f};
    const int dcol = wid * 16 + lrow;
#pragma unroll
    for (int ks = 0; ks < 2; ++ks) {
      const int gran = ks * 4 + kgrp;
      bf16x8 afr = *(const bf16x8*)(lds + HL_O + lrow * 128 +
                                    ((gran ^ (lrow & 7)) << 4));
      bf16x8 bfr = *(const bf16x8*)(w2bf + dcol * 64 + gran * 8);
      acc_l = __builtin_amdgcn_mfma_f32_16x16x32_bf16(afr, bfr, acc_l, 0, 0, 0);
    }
    float b2v = dh_b2[dcol];
    float* dp = (float*)(lds + DP_O);
#pragma unroll
    for (int rr = 0; rr < 4; ++rr) {
      int px = kgrp * 4 + rr;
      if (px < 14) dp[px * 33 + dcol] = acc_l[rr] + b2v;
    }
  }
  __syncthreads();  // barrier 3

  // ---- wave-parallel softmax: 8 lanes per px, 4 depths each ----
  {
    float* dp = (float*)(lds + DP_O);
    int px = tid >> 3, dg = tid & 7;
    if (px < 14) {
      float l0 = dp[px * 33 + dg * 4 + 0];
      float l1 = dp[px * 33 + dg * 4 + 1];
      float l2 = dp[px * 33 + dg * 4 + 2];
      float l3 = dp[px * 33 + dg * 4 + 3];
      float mx = fmaxf(fmaxf(l0, l1), fmaxf(l2, l3));
      mx = fmaxf(mx, __shfl_xor(mx, 1));
      mx = fmaxf(mx, __shfl_xor(mx, 2));
      mx = fmaxf(mx, __shfl_xor(mx, 4));
      float e0 = expf(l0 - mx), e1 = expf(l1 - mx);
      float e2 = expf(l2 - mx), e3 = expf(l3 - mx);
      float s = (e0 + e1) + (e2 + e3);
      s += __shfl_xor(s, 1);
      s += __shfl_xor(s, 2);
      s += __shfl_xor(s, 4);
      float inv = trust[n] / s;
      dp[px * 33 + dg * 4 + 0] = e0 * inv;
      dp[px * 33 + dg * 4 + 1] = e1 * inv;
      dp[px * 33 + dg * 4 + 2] = e2 * inv;
      dp[px * 33 + dg * 4 + 3] = e3 * inv;
    }
  }
  __syncthreads();  // barrier 4

  // ---- partial G[d][c] = sum_{r in half} dp[r][d]*F[r][c] ----
  {
    const int d = tid >> 3, cg = tid & 7;
    if (vL[d]) {
      const float* dp = (const float*)(lds + DP_O);
      const float* FLf = (const float*)(lds + FL_O);
      float a[16];
#pragma unroll
      for (int j = 0; j < 16; ++j) a[j] = 0.f;
      for (int r = 0; r < 14; ++r) {
        float dv = dp[r * 33 + d];
        const float4* fr = (const float4*)(FLf + r * 132 + cg * 16);
        float4 f0 = fr[0], f1 = fr[1], f2 = fr[2], f3 = fr[3];
        a[0] = fmaf(dv, f0.x, a[0]);   a[1] = fmaf(dv, f0.y, a[1]);
        a[2] = fmaf(dv, f0.z, a[2]);   a[3] = fmaf(dv, f0.w, a[3]);
        a[4] = fmaf(dv, f1.x, a[4]);   a[5] = fmaf(dv, f1.y, a[5]);
        a[6] = fmaf(dv, f1.z, a[6]);   a[7] = fmaf(dv, f1.w, a[7]);
        a[8] = fmaf(dv, f2.x, a[8]);   a[9] = fmaf(dv, f2.y, a[9]);
        a[10] = fmaf(dv, f2.z, a[10]); a[11] = fmaf(dv, f2.w, a[11]);
        a[12] = fmaf(dv, f3.x, a[12]); a[13] = fmaf(dv, f3.y, a[13]);
        a[14] = fmaf(dv, f3.z, a[14]); a[15] = fmaf(dv, f3.w, a[15]);
      }
      float* gw = (float*)(lds + G_O) + d * 128 + cg * 16;
#pragma unroll
      for (int j = 0; j < 16; ++j) gw[j] = a[j];
    }
  }
  __syncthreads();  // barrier 5

  // ---- coalesced atomics: lanes = contiguous channels; staggered d ----
  {
    const int hd = tid >> 7;
    const int c = tid & 127;
    const int b = n / 6;
    const float* Gf = (const float*)(lds + G_O);
    float* bb = bev + ((size_t)b * (BH * BW)) * CB + c;
    for (int it = 0; it < 16; ++it) {
      int d = ((it + (int)blockIdx.x) & 15) * 2 + hd;
      if (vL[d])
        atomicAdd(bb + ((size_t)rowL[d] * BW + colL[d]) * CB, Gf[d * 128 + c]);
    }
  }
}

// ---------------- BEV 3x3 conv via bf16 MFMA: 8x4 tiles, 1024 blocks --------
// wt2: fragment-ordered [tap][ks][cb][lane][8]. B-frags direct from L2.
template <int IN_F32, int OUT_NCHW>
__global__ __launch_bounds__(256, 4) void k_bev_conv_mfma(
    const void* __restrict__ inp, const __bf16* __restrict__ wt2,
    const float* __restrict__ bias, const float* __restrict__ g,
    const float* __restrict__ be, const float* __restrict__ m,
    const float* __restrict__ v, void* __restrict__ outp) {
  __shared__ __align__(16) unsigned char ldsA[60 * CB * 2];  // 15360: 6x10 halo
  __shared__ float lo[OUT_NCHW ? 32 * 130 : 4];

  const int blk = blockIdx.x;
  const int tx = blk & 15;
  const int ty = (blk >> 4) & 31;
  const int b = blk >> 9;
  const int y0 = ty * 4, x0 = tx * 8;

  const int l = threadIdx.x & 63;
  const int wid = threadIdx.x >> 6;
  const int lrow = l & 15;
  const int kgrp = l >> 4;

  // ---- stage A: 6 rows x 10 cols halo x 128ci bf16, swizzled ----
  for (int i = threadIdx.x; i < 960; i += 256) {
    int q = i >> 4;
    int ch = i & 15;
    int hy = q / 10, hx = q % 10;
    int gy = y0 + hy - 1, gx = x0 + hx - 1;
    bf16x8 val;
    if (gy >= 0 && gy < BH && gx >= 0 && gx < BW) {
      if (IN_F32) {
        const float* ib = (const float*)inp + (size_t)b * BH * BW * CB;
        const float* sp = ib + ((size_t)gy * BW + gx) * CB + ch * 8;
        float4 a = *(const float4*)sp;
        float4 bb = *(const float4*)(sp + 4);
        __bf16 tmp[8] = {(__bf16)a.x,  (__bf16)a.y,  (__bf16)a.z,  (__bf16)a.w,
                         (__bf16)bb.x, (__bf16)bb.y, (__bf16)bb.z, (__bf16)bb.w};
        val = *(bf16x8*)tmp;
      } else {
        const __bf16* ib = (const __bf16*)inp + (size_t)b * BH * BW * CB;
        val = *(const bf16x8*)(ib + ((size_t)gy * BW + gx) * CB + ch * 8);
      }
    } else {
      __bf16 tmp[8] = {(__bf16)0.f, (__bf16)0.f, (__bf16)0.f, (__bf16)0.f,
                       (__bf16)0.f, (__bf16)0.f, (__bf16)0.f, (__bf16)0.f};
      val = *(bf16x8*)tmp;
    }
    int byte = (q * 256 + ch * 16) ^ ((q & 7) << 4);
    *(bf16x8*)(ldsA + byte) = val;
  }
  __syncthreads();

  // ---- MFMA: M=32 px (shared), N=128 co (32/wave), K=1152 ----
  f32x4 acc[2][2];
#pragma unroll
  for (int i = 0; i < 2; ++i)
#pragma unroll
    for (int j = 0; j < 2; ++j) acc[i][j] = {0.f, 0.f, 0.f, 0.f};

#pragma unroll
  for (int tap = 0; tap < 9; ++tap) {
    const int ky = tap / 3, kx = tap % 3;
#pragma unroll
    for (int ks = 0; ks < 4; ++ks) {
      const int ci0b = (ks * 32 + kgrp * 8) * 2;
      bf16x8 afr[2], bfr[2];
#pragma unroll
      for (int fm = 0; fm < 2; ++fm) {
        int mpx = fm * 16 + lrow;
        int q = ((mpx >> 3) + ky) * 10 + (mpx & 7) + kx;
        int byte = (q * 256 + ci0b) ^ ((q & 7) << 4);
        afr[fm] = *(const bf16x8*)(ldsA + byte);
      }
#pragma unroll
      for (int fn = 0; fn < 2; ++fn) {
        int frag = (tap * 4 + ks) * 8 + (wid * 2 + fn);
        bfr[fn] = *(const bf16x8*)(wt2 + ((size_t)frag << 9) + (l << 3));
      }
#pragma unroll
      for (int fm = 0; fm < 2; ++fm)
#pragma unroll
        for (int fn = 0; fn < 2; ++fn)
          acc[fm][fn] = __builtin_amdgcn_mfma_f32_16x16x32_bf16(
              afr[fm], bfr[fn], acc[fm][fn], 0, 0, 0);
    }
  }

  if (OUT_NCHW == 0) {
    __bf16* out = (__bf16*)outp;
#pragma unroll
    for (int fn = 0; fn < 2; ++fn) {
      int co = wid * 32 + fn * 16 + lrow;
      float sc = g[co] / sqrtf(v[co] + BEPS);
      float sh = be[co] - m[co] * sc + bias[co] * sc;
#pragma unroll
      for (int fm = 0; fm < 2; ++fm) {
#pragma unroll
        for (int r = 0; r < 4; ++r) {
          int mpx = fm * 16 + kgrp * 4 + r;
          int y = y0 + (mpx >> 3), x = x0 + (mpx & 7);
          float val = gelu_exact(acc[fm][fn][r] * sc + sh);
          out[((size_t)(b * BH + y) * BW + x) * CB + co] = (__bf16)val;
        }
      }
    }
  } else {
#pragma unroll
    for (int fn = 0; fn < 2; ++fn) {
      int co = wid * 32 + fn * 16 + lrow;
      float sc = g[co] / sqrtf(v[co] + BEPS);
      float sh = be[co] - m[co] * sc + bias[co] * sc;
#pragma unroll
      for (int fm = 0; fm < 2; ++fm) {
#pragma unroll
        for (int r = 0; r < 4; ++r) {
          int mpx = fm * 16 + kgrp * 4 + r;
          lo[mpx * 130 + co] = gelu_exact(acc[fm][fn][r] * sc + sh);
        }
      }
    }
    __syncthreads();
    float* out = (float*)outp;
    for (int pair = threadIdx.x; pair < 512; pair += 256) {
      int co = pair >> 2, py = pair & 3;
      float tmp[8];
#pragma unroll
      for (int i = 0; i < 8; ++i) tmp[i] = lo[(py * 8 + i) * 130 + co];
      float* op = out + (((size_t)(b * CB + co) * BH) + (y0 + py)) * BW + x0;
      *(float4*)op = *(float4*)tmp;
      *(float4*)(op + 4) = *(float4*)(tmp + 4);
    }
  }
}

extern "C" void kernel_launch(void* const* d_in, const int* in_sizes, int n_in,
                              void* d_out, int out_size, void* d_ws, size_t ws_size,
                              hipStream_t stream) {
  const float* feat = (const float*)d_in[0];
  const float* Kmat = (const float*)d_in[1];
  const float* Tmat = (const float*)d_in[2];
  const float* trust = (const float*)d_in[3];
  const float* dh_w1 = (const float*)d_in[4];
  const float* dh_b1 = (const float*)d_in[5];
  const float* dh_g = (const float*)d_in[6];
  const float* dh_be = (const float*)d_in[7];
  const float* dh_m = (const float*)d_in[8];
  const float* dh_v = (const float*)d_in[9];
  const float* dh_w2 = (const float*)d_in[10];
  const float* dh_b2 = (const float*)d_in[11];
  const float* fp_w = (const float*)d_in[12];
  const float* fp_b = (const float*)d_in[13];
  const float* fp_g = (const float*)d_in[14];
  const float* fp_be = (const float*)d_in[15];
  const float* fp_m = (const float*)d_in[16];
  const float* fp_v = (const float*)d_in[17];
  const float* br_w1 = (const float*)d_in[18];
  const float* br_b1 = (const float*)d_in[19];
  const float* br_g1 = (const float*)d_in[20];
  const float* br_be1 = (const float*)d_in[21];
  const float* br_m1 = (const float*)d_in[22];
  const float* br_v1 = (const float*)d_in[23];
  const float* br_w2 = (const float*)d_in[24];
  const float* br_b2 = (const float*)d_in[25];
  const float* br_g2 = (const float*)d_in[26];
  const float* br_be2 = (const float*)d_in[27];
  const float* br_m2 = (const float*)d_in[28];
  const float* br_v2 = (const float*)d_in[29];

  float* ws = (float*)d_ws;
  float* bev = ws;                                       // 4,194,304 f
  float* after = bev + 4194304;
  __bf16* h1bf = (__bf16*)after;                         // 4,194,304 bf16
  __bf16* w1dh = (__bf16*)(after + 2097152);             // 36,864 bf16
  __bf16* w1bev = (__bf16*)(after + 2097152 + 18432);    // 147,456 bf16 (frag order)
  __bf16* w2bev = (__bf16*)(after + 2097152 + 18432 + 73728);        // 147,456
  __bf16* wfpbf = (__bf16*)(after + 2097152 + 18432 + 2 * 73728);    // 8,192
  __bf16* w2bf = (__bf16*)(after + 2097152 + 18432 + 2 * 73728 + 4096);  // 2,048
  __bf16* featT = (__bf16*)(after + 2097152 + 18432 + 2 * 73728 + 4096 + 1024);

  // prep: transpose + weight preps + bev zero (1 dispatch)
  k_prep<<<5696, 256, 0, stream>>>(feat, dh_w1, br_w1, br_w2, fp_w, dh_w2,
                                   featT, w1dh, w1bev, w2bev, wfpbf, w2bf, bev);
  // fused front v5 (row-split: 1200 blocks)
  k_mega<<<N_IMG * WFEAT * 2, 256, 0, stream>>>(
      featT, w1dh, dh_b1, dh_g, dh_be, dh_m, dh_v, w2bf, dh_b2, wfpbf, fp_b,
      fp_g, fp_be, fp_m, fp_v, trust, Kmat, Tmat, bev);
  // BEV refinement convs via MFMA (8x4 tiles: 1024 blocks each)
  k_bev_conv_mfma<1, 0><<<1024, 256, 0, stream>>>(
      (const void*)bev, w1bev, br_b1, br_g1, br_be1, br_m1, br_v1, (void*)h1bf);
  k_bev_conv_mfma<0, 1><<<1024, 256, 0, stream>>>(
      (const void*)h1bf, w2bev, br_b2, br_g2, br_be2, br_m2, br_v2, d_out);
}